// Round 1
// baseline (482.156 us; speedup 1.0000x reference)
//
#include <hip/hip_runtime.h>
#include <math.h>

#define EPS 1e-5f
#define RT 8  // rows per block in lbr_kernel

__device__ __forceinline__ float gelu_exact(float x) {
    return 0.5f * x * (1.0f + erff(x * 0.7071067811865476f));
}

// ---- block reductions (all threads must call; red needs >= blockDim/64 floats) ----
__device__ float block_sum(float v, float* red) {
    int lane = threadIdx.x & 63, wid = threadIdx.x >> 6;
#pragma unroll
    for (int off = 32; off > 0; off >>= 1) v += __shfl_down(v, off, 64);
    if (lane == 0) red[wid] = v;
    __syncthreads();
    int nw = ((int)blockDim.x + 63) >> 6;
    float s = red[0];
    for (int w = 1; w < nw; w++) s += red[w];
    __syncthreads();
    return s;
}

__device__ float block_max(float v, float* red) {
    int lane = threadIdx.x & 63, wid = threadIdx.x >> 6;
#pragma unroll
    for (int off = 32; off > 0; off >>= 1) v = fmaxf(v, __shfl_down(v, off, 64));
    if (lane == 0) red[wid] = v;
    __syncthreads();
    int nw = ((int)blockDim.x + 63) >> 6;
    float s = red[0];
    for (int w = 1; w < nw; w++) s = fmaxf(s, red[w]);
    __syncthreads();
    return s;
}

// ---- threefry2x32-20 (JAX PRNG) ----
__device__ void threefry2x32(unsigned k0, unsigned k1, unsigned x0, unsigned x1,
                             unsigned& o0, unsigned& o1) {
    unsigned ks[3] = {k0, k1, k0 ^ k1 ^ 0x1BD11BDAu};
    const unsigned rot[2][4] = {{13u, 15u, 26u, 6u}, {17u, 29u, 16u, 24u}};
    x0 += ks[0]; x1 += ks[1];
#pragma unroll
    for (int i = 0; i < 5; i++) {
#pragma unroll
        for (int j = 0; j < 4; j++) {
            unsigned r = rot[i & 1][j];
            x0 += x1;
            x1 = (x1 << r) | (x1 >> (32 - r));
            x1 ^= x0;
        }
        x0 += ks[(i + 1) % 3];
        x1 += ks[(i + 2) % 3] + (unsigned)(i + 1);
    }
    o0 = x0; o1 = x1;
}

// jax.random.gumbel(key(42), (32,8), f32), partitionable threefry (JAX >= 0.5 default):
// bits[j] = o0 ^ o1 with counter (hi=0, lo=j).
__device__ float gumbel_at(int j) {
    unsigned o0, o1;
    threefry2x32(0u, 42u, 0u, (unsigned)j, o0, o1);
    unsigned bits = o0 ^ o1;
    float f = __uint_as_float((bits >> 9) | 0x3F800000u) - 1.0f;  // [0,1)
    float u = fmaxf(f + 1.17549435e-38f, 1.17549435e-38f);
    return -logf(-logf(u));
}

// ---- encode: x -= x[:,0]; moving-avg(k=25, replicate); two C=9->H=128 linears
//      + per-(b,l) instance-norm over H + exact GELU; sum branches. ----
// grid (L, B), block 128 threads (t == h).
__global__ void encode_kernel(const float* __restrict__ x, int L,
                              const float* __restrict__ Ws, const float* __restrict__ bs,
                              const float* __restrict__ Wt, const float* __restrict__ bt,
                              float* __restrict__ e) {
    const int C = 9, H = 128;
    int l = blockIdx.x, b = blockIdx.y, t = threadIdx.x;
    __shared__ float seas[9], mmv[9];
    __shared__ float red[4];
    const float* xb = x + (size_t)b * L * C;
    if (t < C) {
        float x0 = xb[t];
        float s = 0.f;
        for (int j = -12; j <= 12; j++) {
            int lj = l + j;
            lj = lj < 0 ? 0 : (lj >= L ? L - 1 : lj);
            s += xb[(size_t)lj * C + t] - x0;
        }
        float mm = s * (1.0f / 25.0f);
        float xd = xb[(size_t)l * C + t] - x0;
        mmv[t] = mm;
        seas[t] = xd - mm;
    }
    __syncthreads();
    float ys = bs[t], yt = bt[t];
#pragma unroll
    for (int c = 0; c < 9; c++) {
        ys += seas[c] * Ws[c * H + t];
        yt += mmv[c] * Wt[c * H + t];
    }
    float m = block_sum(ys, red) * (1.0f / 128.0f);
    float d = ys - m;
    float v = block_sum(d * d, red) * (1.0f / 128.0f);
    float gy = gelu_exact(d * rsqrtf(v + EPS));
    m = block_sum(yt, red) * (1.0f / 128.0f);
    d = yt - m;
    v = block_sum(d * d, red) * (1.0f / 128.0f);
    float gt = gelu_exact(d * rsqrtf(v + EPS));
    e[((size_t)b * L + l) * H + t] = gy + gt;
}

// ---- generic Linear -> InstanceNorm(over N) -> GELU over a strided input view.
// in[b][r][k] at in + b*in_bstride + r*rs + k*ks. out row-major (ROWS x N) per b.
// grid (ROWS/RT, B), block N threads, dyn-shmem (RT*K + 4) floats.
__global__ void lbr_kernel(const float* __restrict__ in, int in_bstride,
                           int rs, int ks, int K, int N,
                           const float* __restrict__ W, const float* __restrict__ bias,
                           float* __restrict__ out) {
    extern __shared__ float sm[];
    float* tile = sm;           // RT*K
    float* red = sm + RT * K;   // 4
    int b = blockIdx.y;
    int r0 = blockIdx.x * RT;
    int n = threadIdx.x;  // < N
    const float* inb = in + (size_t)b * in_bstride;
    int total = RT * K;
    if (ks == 1) {
        for (int idx = n; idx < total; idx += N) {
            int r = idx / K, k = idx - r * K;
            tile[r * K + k] = inb[(size_t)(r0 + r) * rs + k];
        }
    } else {  // rs == 1
        for (int idx = n; idx < total; idx += N) {
            int r = idx & (RT - 1), k = idx >> 3;
            tile[r * K + k] = inb[(r0 + r) + (size_t)k * ks];
        }
    }
    __syncthreads();
    float acc[RT];
#pragma unroll
    for (int r = 0; r < RT; r++) acc[r] = bias[n];
    for (int k = 0; k < K; k++) {
        float wv = W[(size_t)k * N + n];
#pragma unroll
        for (int r = 0; r < RT; r++) acc[r] += tile[r * K + k] * wv;
    }
    float invN = 1.0f / (float)N;
    float* outb = out + (size_t)b * (size_t)gridDim.x * RT * N;
    for (int r = 0; r < RT; r++) {
        float m = block_sum(acc[r], red) * invN;
        float d = acc[r] - m;
        float v = block_sum(d * d, red) * invN;
        outb[(size_t)(r0 + r) * N + n] = gelu_exact(d * rsqrtf(v + EPS));
    }
}

// ---- logits (B x 8) from O6 (B,128,64 laid out [h,l4]) @ Wr(8192,8)+br,
// then gumbel-softmax(hard): store argmax regime + weight (1-s)+s. ----
// grid 32, block 256.
__global__ void logits_kernel(const float* __restrict__ O6, const float* __restrict__ Wr,
                              const float* __restrict__ br,
                              float* __restrict__ sel_w, int* __restrict__ sel_r) {
    int b = blockIdx.x, t = threadIdx.x;
    __shared__ float red[4];
    __shared__ float lg[8];
    const float* ob = O6 + (size_t)b * 8192;
    float acc[8] = {0, 0, 0, 0, 0, 0, 0, 0};
    for (int i = t; i < 8192; i += 256) {
        int l4 = i >> 7, h = i & 127;  // flat index i = l4*128 + h
        float v = ob[h * 64 + l4];
        const float* wrow = Wr + (size_t)i * 8;
#pragma unroll
        for (int j = 0; j < 8; j++) acc[j] += v * wrow[j];
    }
    for (int j = 0; j < 8; j++) {
        float s = block_sum(acc[j], red);
        if (t == 0) lg[j] = s + br[j];
    }
    __syncthreads();
    if (t == 0) {
        float z[8];
        for (int j = 0; j < 8; j++) z[j] = lg[j] + gumbel_at(b * 8 + j);
        int am = 0;
        float zm = z[0];
        for (int j = 1; j < 8; j++)
            if (z[j] > zm) { zm = z[j]; am = j; }
        float ssum = 0.f;
        for (int j = 0; j < 8; j++) ssum += expf(z[j] - zm);
        float s = 1.0f / ssum;        // y_soft at argmax
        sel_w[b] = (1.0f - s) + s;    // matches (y_hard - y_soft) + y_soft fp order
        sel_r[b] = am;
    }
}

// ---- partial einsum: part[b,ch,mo] = sum over n in chunk, h of
//      e_st[b,n,h] * proto[r_b, n, h, m, o].  grid (16, B), block 192. ----
__global__ void einsum_kernel(const float* __restrict__ e_st, const float* __restrict__ proto,
                              const int* __restrict__ sel_r, float* __restrict__ part) {
    int ch = blockIdx.x, b = blockIdx.y, t = threadIdx.x;  // t = m*3+o
    __shared__ float es[8 * 128];
    const float* eb = e_st + ((size_t)b * 128 + ch * 8) * 128;
    for (int i = t; i < 1024; i += 192) es[i] = eb[i];
    __syncthreads();
    int r = sel_r[b];
    const float* pb = proto + ((size_t)r * 128 + ch * 8) * 128 * 192;
    float acc = 0.f;
    for (int i = 0; i < 1024; i++) acc += es[i] * pb[(size_t)i * 192 + t];
    part[((size_t)b * 16 + ch) * 192 + t] = acc;
}

// ---- reduce chunks, scale by regime weight, softmax over 192. grid 32, block 192. ----
__global__ void finalize_kernel(const float* __restrict__ part, const float* __restrict__ sel_w,
                                float* __restrict__ out) {
    int b = blockIdx.x, t = threadIdx.x;
    __shared__ float red[4];
    float v = 0.f;
    for (int c = 0; c < 16; c++) v += part[((size_t)b * 16 + c) * 192 + t];
    v *= sel_w[b];
    float mx = block_max(v, red);
    float e = expf(v - mx);
    float s = block_sum(e, red);
    out[(size_t)b * 192 + t] = e / s;
}

extern "C" void kernel_launch(void* const* d_in, const int* in_sizes, int n_in,
                              void* d_out, int out_size, void* d_ws, size_t ws_size,
                              hipStream_t stream) {
    const float* in_lt = (const float*)d_in[0];
    const float* in_st = (const float*)d_in[1];
    const float* Ws  = (const float*)d_in[2];  const float* bs  = (const float*)d_in[3];
    const float* Wt  = (const float*)d_in[4];  const float* bt  = (const float*)d_in[5];
    const float* Wh1 = (const float*)d_in[6];  const float* bh1 = (const float*)d_in[7];
    const float* Wl1 = (const float*)d_in[8];  const float* bl1 = (const float*)d_in[9];
    const float* Wh2 = (const float*)d_in[10]; const float* bh2 = (const float*)d_in[11];
    const float* Wl2 = (const float*)d_in[12]; const float* bl2 = (const float*)d_in[13];
    const float* Wh3 = (const float*)d_in[14]; const float* bh3 = (const float*)d_in[15];
    const float* Wl3 = (const float*)d_in[16]; const float* bl3 = (const float*)d_in[17];
    const float* Wr  = (const float*)d_in[18]; const float* br  = (const float*)d_in[19];
    const float* proto = (const float*)d_in[20];
    float* out = (float*)d_out;

    float* ws = (float*)d_ws;
    size_t off = 0;
    float* e_lt = ws + off; off += (size_t)32 * 512 * 128;  // [l,h]
    float* e_st = ws + off; off += (size_t)32 * 128 * 128;  // [n,h]
    float* O1 = ws + off; off += (size_t)32 * 512 * 128;    // [l, h]
    float* O2 = ws + off; off += (size_t)32 * 128 * 256;    // [h, l2]
    float* O3 = ws + off; off += (size_t)32 * 256 * 128;    // [l2, h]
    float* O4 = ws + off; off += (size_t)32 * 128 * 128;    // [h, l3]
    float* O5 = ws + off; off += (size_t)32 * 128 * 128;    // [l3, h]
    float* O6 = ws + off; off += (size_t)32 * 128 * 64;     // [h, l4]
    float* part = ws + off; off += (size_t)32 * 16 * 192;
    float* sel_w = ws + off; off += 32;
    int* sel_r = (int*)(ws + off); off += 32;

    encode_kernel<<<dim3(512, 32), 128, 0, stream>>>(in_lt, 512, Ws, bs, Wt, bt, e_lt);
    encode_kernel<<<dim3(128, 32), 128, 0, stream>>>(in_st, 128, Ws, bs, Wt, bt, e_st);
    // h1: rows=l(512), K=h(128), N=128
    lbr_kernel<<<dim3(64, 32), 128, (8 * 128 + 4) * 4, stream>>>(
        e_lt, 512 * 128, 128, 1, 128, 128, Wh1, bh1, O1);
    // l1: rows=h(128), K=l(512), N=256 ; in view of O1 [l,h]
    lbr_kernel<<<dim3(16, 32), 256, (8 * 512 + 4) * 4, stream>>>(
        O1, 512 * 128, 1, 128, 512, 256, Wl1, bl1, O2);
    // h2: rows=l2(256), K=h(128), N=128 ; in view of O2 [h,l2]
    lbr_kernel<<<dim3(32, 32), 128, (8 * 128 + 4) * 4, stream>>>(
        O2, 128 * 256, 1, 256, 128, 128, Wh2, bh2, O3);
    // l2: rows=h(128), K=l2(256), N=128 ; in view of O3 [l2,h]
    lbr_kernel<<<dim3(16, 32), 128, (8 * 256 + 4) * 4, stream>>>(
        O3, 256 * 128, 1, 128, 256, 128, Wl2, bl2, O4);
    // h3: rows=l3(128), K=h(128), N=128 ; in view of O4 [h,l3]
    lbr_kernel<<<dim3(16, 32), 128, (8 * 128 + 4) * 4, stream>>>(
        O4, 128 * 128, 1, 128, 128, 128, Wh3, bh3, O5);
    // l3: rows=h(128), K=l3(128), N=64 ; in view of O5 [l3,h]
    lbr_kernel<<<dim3(16, 32), 64, (8 * 128 + 4) * 4, stream>>>(
        O5, 128 * 128, 1, 128, 128, 64, Wl3, bl3, O6);
    logits_kernel<<<32, 256, 0, stream>>>(O6, Wr, br, sel_w, sel_r);
    einsum_kernel<<<dim3(16, 32), 192, 0, stream>>>(e_st, proto, sel_r, part);
    finalize_kernel<<<32, 192, 0, stream>>>(part, sel_w, out);
}